// Round 10
// baseline (294.449 us; speedup 1.0000x reference)
//
#include <hip/hip_runtime.h>
#include <hip/hip_bf16.h>
#include <stdint.h>

#define N1 8192
#define N2 16384
#define DIM 256
#define NSPLIT 16
#define BM 128
#define BN 128
#define BK 128
#define COLS_PER_SPLIT (N2 / NSPLIT)        // 1024
#define NT_PER_SPLIT (COLS_PER_SPLIT / BN)  // 8
#define NPART (NSPLIT * 2)                  // 32 partial top3 sets per row
#define NRB (N1 / BM)                       // 64 row-blocks

typedef short v8s  __attribute__((ext_vector_type(8)));   // 8 x bf16 bits
typedef float f32x4 __attribute__((ext_vector_type(4)));

#define GLD16(g, l)                                                                         \
  __builtin_amdgcn_global_load_lds((const __attribute__((address_space(1))) uint32_t*)(g),  \
                                   (__attribute__((address_space(3))) uint32_t*)(l), 16, 0, 0)

__device__ __forceinline__ void top3_insert(float v, float& t0, float& t1, float& t2) {
    // invariant t0 >= t1 >= t2; 3 VALU ops
    float nt1 = __builtin_amdgcn_fmed3f(v, t0, t1);
    float nt2 = __builtin_amdgcn_fmed3f(v, t1, t2);
    t0 = fmaxf(t0, v);
    t1 = nt1;
    t2 = nt2;
}

// One wave per row over A then B: fp32 sumsq, rsqrt, emit bf16 normalized row.
// Also zeroes the rb-completion counters used by the fused merge (this kernel
// always precedes gemm on the stream, and runs every call).
__global__ __launch_bounds__(256) void normalize_kernel(
        const float* __restrict__ inA, const float* __restrict__ inB,
        __hip_bfloat16* __restrict__ outA, __hip_bfloat16* __restrict__ outB,
        int* __restrict__ cnt) {
    if (blockIdx.x == 0 && threadIdx.x < NRB) cnt[threadIdx.x] = 0;
    const int gw   = blockIdx.x * 4 + (threadIdx.x >> 6);
    const int lane = threadIdx.x & 63;
    const float* in;
    __hip_bfloat16* out;
    int row;
    if (gw < N1) { in = inA; out = outA; row = gw; }
    else         { in = inB; out = outB; row = gw - N1; }
    const float4 v = *(const float4*)(in + (size_t)row * DIM + lane * 4);
    float s = v.x * v.x + v.y * v.y + v.z * v.z + v.w * v.w;
    #pragma unroll
    for (int off = 32; off; off >>= 1) s += __shfl_xor(s, off, 64);
    const float inv = 1.0f / sqrtf(s);
    __hip_bfloat16 o[4];
    o[0] = __float2bfloat16(v.x * inv);
    o[1] = __float2bfloat16(v.y * inv);
    o[2] = __float2bfloat16(v.z * inv);
    o[3] = __float2bfloat16(v.w * inv);
    *(uint2*)(out + (size_t)row * DIM + lane * 4) = *(uint2*)o;
}

// Block: 4 waves over a 128x128 C-tile; wave = 64x64 (4rt x 4ct of 16x16).
// BK=128: per K-chunk A 128x128 (32 KB) + B 128x128 (32 KB) staged via
// global_load_lds width=16. Register-capped at 2 blocks/CU (112 VGPR + 64
// AGPR acc ~176/wave), so 64 KB LDS costs no occupancy and halves the
// exposed vmcnt(0) drains vs BK=64. XOR swizzle slot16 = chunk ^ (row&15)
// folded into the global-side lane permutation -> free ds_read_b128.
// The last block of each row-block (device-scope counter) merges the 32
// partial top3 sets per row inline -> no separate merge launch.
__global__ __launch_bounds__(256, 2) void gemm_top3_kernel(
        const __hip_bfloat16* __restrict__ A, const __hip_bfloat16* __restrict__ B,
        float* __restrict__ partial, float* __restrict__ out, int* __restrict__ cnt) {
    __shared__ char smem[32768 + 32768];
    char* tileA = smem;             // [128 rows][16 slots of 16B]  row stride 256 B
    char* tileB = smem + 32768;     // [128 cols][16 slots of 16B]

    const int tid  = threadIdx.x;
    const int wave = tid >> 6;
    const int lane = tid & 63;
    const int lo   = lane & 15;
    const int quad = lane >> 4;
    const int rb    = blockIdx.x >> 4;     // 64 row-blocks
    const int split = blockIdx.x & 15;     // consecutive blocks -> different XCDs
    const int row0 = rb * BM;
    const int C0   = split * COLS_PER_SPLIT;
    const int wr = (wave >> 1) * 64;       // wave row-half
    const int wc = (wave & 1) * 64;        // wave col-half

    // --- staging lane constants (16 lanes span one row's 16 slots of 16B) ---
    const int lr  = lane >> 4;             // 0..3 : row-within-round
    const int s16 = lane & 15;             // 0..15: physical LDS slot

    const char* Agbase = (const char*)A + ((size_t)(row0 + wave * 32 + lr)) * 512;
    const char* Bgbase = (const char*)B + ((size_t)(C0   + wave * 32 + lr)) * 512;
    char* AldsBase = tileA + wave * 32 * 256;   // + j*1024 per 4-row round
    char* BldsBase = tileB + wave * 32 * 256;

    // --- ds_read offsets (swizzle: slot = (ks*4+quad) ^ (row&15)) ---
    int aoff[4], boff[4];
    #pragma unroll
    for (int ks = 0; ks < 4; ks++) {
        const int swz = ((ks * 4 + quad) ^ lo) * 16;
        aoff[ks] = (wr + lo) * 256 + swz;
        boff[ks] = (wc + lo) * 256 + swz;
    }

    float t0[16], t1[16], t2[16];
    #pragma unroll
    for (int i = 0; i < 16; i++) { t0[i] = -1e30f; t1[i] = -1e30f; t2[i] = -1e30f; }

    for (int nt = 0; nt < NT_PER_SPLIT; ++nt) {
        f32x4 acc[4][4];
        #pragma unroll
        for (int kk = 0; kk < 2; kk++) {
            __syncthreads();   // previous round's ds_reads done; buffers free
            #pragma unroll
            for (int j = 0; j < 8; j++) {
                const int sxj = (s16 ^ ((j * 4 + lr) & 15)) * 16;
                GLD16(Agbase + (size_t)j * 2048 + kk * 256 + sxj, AldsBase + j * 1024);
                GLD16(Bgbase + (size_t)nt * 65536 + (size_t)j * 2048 + kk * 256 + sxj,
                      BldsBase + j * 1024);
            }
            __syncthreads();   // staging drained (vmcnt(0) before barrier)
            #pragma unroll
            for (int ks = 0; ks < 4; ks++) {
                v8s af[4];
                #pragma unroll
                for (int rt = 0; rt < 4; rt++)
                    af[rt] = *(const v8s*)(tileA + aoff[ks] + rt * 4096);
                #pragma unroll
                for (int ct = 0; ct < 4; ct++) {
                    v8s bf = *(const v8s*)(tileB + boff[ks] + ct * 4096);
                    #pragma unroll
                    for (int rt = 0; rt < 4; rt++) {
                        if (kk == 0 && ks == 0)
                            acc[rt][ct] = __builtin_amdgcn_mfma_f32_16x16x32_bf16(
                                af[rt], bf, (f32x4){0.f, 0.f, 0.f, 0.f}, 0, 0, 0);
                        else
                            acc[rt][ct] = __builtin_amdgcn_mfma_f32_16x16x32_bf16(
                                af[rt], bf, acc[rt][ct], 0, 0, 0);
                    }
                }
            }
        }
        // fold this N-tile's 64 C-values/lane into the running top3
        #pragma unroll
        for (int rt = 0; rt < 4; rt++)
            #pragma unroll
            for (int r = 0; r < 4; r++) {
                const int i = rt * 4 + r;
                #pragma unroll
                for (int ct = 0; ct < 4; ct++)
                    top3_insert(acc[rt][ct][r], t0[i], t1[i], t2[i]);
            }
    }

    // merge across the 16 lanes sharing rows (different col residues)
    #pragma unroll
    for (int step = 1; step < 16; step <<= 1) {
        #pragma unroll
        for (int i = 0; i < 16; i++) {
            float b0 = __shfl_xor(t0[i], step, 64);
            float b1 = __shfl_xor(t1[i], step, 64);
            float b2 = __shfl_xor(t2[i], step, 64);
            top3_insert(b0, t0[i], t1[i], t2[i]);
            top3_insert(b1, t0[i], t1[i], t2[i]);
            top3_insert(b2, t0[i], t1[i], t2[i]);
        }
    }

    if (lo == 0) {
        #pragma unroll
        for (int rt = 0; rt < 4; rt++)
            #pragma unroll
            for (int r = 0; r < 4; r++) {
                const int i = rt * 4 + r;
                const int row = row0 + wr + rt * 16 + quad * 4 + r;
                float* p = partial + ((size_t)row * NPART + (split * 2 + (wave & 1))) * 3;
                p[0] = t0[i]; p[1] = t1[i]; p[2] = t2[i];
            }
    }

    // --- fused merge: last block of this rb folds all 32 partials per row ---
    __threadfence();                 // make partial writes device-visible
    __syncthreads();                 // all waves' writes issued (LDS use over)
    int* isLastP = (int*)smem;       // reuse dead LDS
    if (tid == 0) {
        int prev = atomicAdd(&cnt[rb], 1);          // device-scope
        *isLastP = (prev == NSPLIT - 1) ? 1 : 0;
    }
    __syncthreads();
    if (*isLastP) {
        __threadfence();             // acquire: no stale cache reads
        if (tid < BM) {
            const int row = row0 + tid;
            const float* p = partial + (size_t)row * NPART * 3;
            float m0 = -1e30f, m1 = -1e30f, m2 = -1e30f;
            #pragma unroll
            for (int i = 0; i < NPART * 3; i++) top3_insert(p[i], m0, m1, m2);
            out[row] = (m0 + m1 + m2) * (1.0f / 3.0f);
        }
    }
}

extern "C" void kernel_launch(void* const* d_in, const int* in_sizes, int n_in,
                              void* d_out, int out_size, void* d_ws, size_t ws_size,
                              hipStream_t stream) {
    const float* tA = (const float*)d_in[0];
    const float* tB = (const float*)d_in[1];
    float* out = (float*)d_out;

    __hip_bfloat16* An = (__hip_bfloat16*)d_ws;
    __hip_bfloat16* Bn = An + (size_t)N1 * DIM;
    float* partial = (float*)(Bn + (size_t)N2 * DIM);
    int* cnt = (int*)(partial + (size_t)N1 * NPART * 3);

    normalize_kernel<<<(N1 + N2) / 4, 256, 0, stream>>>(tA, tB, An, Bn, cnt);
    gemm_top3_kernel<<<(N1 / BM) * NSPLIT, 256, 0, stream>>>(An, Bn, partial, out, cnt);
}

// Round 11
// 242.350 us; speedup vs baseline: 1.2150x; 1.2150x over previous
//
#include <hip/hip_runtime.h>
#include <hip/hip_bf16.h>
#include <stdint.h>

#define N1 8192
#define N2 16384
#define DIM 256
#define NSPLIT 16
#define BM 128
#define BN 128
#define NT_PER_SPLIT 8                      // 1024 cols per split / BN
#define NPART (NSPLIT * 2)                  // 32 partial top3 sets per row

typedef short v8s  __attribute__((ext_vector_type(8)));   // 8 x bf16 bits
typedef float f32x4 __attribute__((ext_vector_type(4)));

#define GLD16(g, l)                                                                         \
  __builtin_amdgcn_global_load_lds((const __attribute__((address_space(1))) uint32_t*)(g),  \
                                   (__attribute__((address_space(3))) uint32_t*)(l), 16, 0, 0)

__device__ __forceinline__ void top3_insert(float v, float& t0, float& t1, float& t2) {
    // invariant t0 >= t1 >= t2; 3 VALU ops
    float nt1 = __builtin_amdgcn_fmed3f(v, t0, t1);
    float nt2 = __builtin_amdgcn_fmed3f(v, t1, t2);
    t0 = fmaxf(t0, v);
    t1 = nt1;
    t2 = nt2;
}

// One wave per row (A rows then B rows): fp32 sumsq, rsqrt, then store the
// bf16 normalized row PRE-PACKED in MFMA fragment order:
//   frag[t][ks][lane] (16 B) = M[row = t*16 + (lane&15)][k = ks*32 + (lane>>4)*8 .. +7]
// flat byte offset ((t*8+ks)*64 + lane)*16. Each lane of the normalize wave
// holds k = lane*4..lane*4+3 (8 B = half of one 16-B frag chunk).
__global__ __launch_bounds__(256) void normalize_repack_kernel(
        const float* __restrict__ inA, const float* __restrict__ inB,
        char* __restrict__ Af, char* __restrict__ Bf) {
    const int gw   = blockIdx.x * 4 + (threadIdx.x >> 6);
    const int lane = threadIdx.x & 63;
    const float* in;
    char* dst;
    int row;
    if (gw < N1) { in = inA; dst = Af; row = gw; }
    else         { in = inB; dst = Bf; row = gw - N1; }
    const float4 v = *(const float4*)(in + (size_t)row * DIM + lane * 4);
    float s = v.x * v.x + v.y * v.y + v.z * v.z + v.w * v.w;
    #pragma unroll
    for (int off = 32; off; off >>= 1) s += __shfl_xor(s, off, 64);
    const float inv = 1.0f / sqrtf(s);
    __hip_bfloat16 o[4];
    o[0] = __float2bfloat16(v.x * inv);
    o[1] = __float2bfloat16(v.y * inv);
    o[2] = __float2bfloat16(v.z * inv);
    o[3] = __float2bfloat16(v.w * inv);
    const int t    = row >> 4;
    const int lo   = row & 15;
    const int ks   = lane >> 3;            // k/32
    const int quad = (lane >> 1) & 3;      // (k%32)/8
    const int half = lane & 1;             // which 8-B half of the 16-B chunk
    const size_t off = ((size_t)(t * 8 + ks) * 64 + quad * 16 + lo) * 16 + half * 8;
    *(uint2*)(dst + off) = *(uint2*)o;
}

// Block: 4 waves over a 128x128 C-tile per nt; wave = 64x64 (4rt x 4ct).
// Barrier-free K-loop: A fragments for K 0..127 live in 64 VGPRs (loaded
// once, coalesced from the frag-packed global layout); K 128..255 live in a
// 32 KB LDS tile staged once via global_load_lds (one __syncthreads total).
// B streams global->VGPR in frag layout (1 KB coalesced per load), L2-hot
// per split-XCD. LDS-read demand drops to ~52 B/cyc (vs 206 in the R7
// structure against ~85 B/cyc ds_read_b128 supply) and no per-chunk
// vmcnt(0)+barrier drains remain.
__global__ __launch_bounds__(256, 2) void gemm_top3_kernel(
        const char* __restrict__ Af, const char* __restrict__ Bf,
        float* __restrict__ partial) {
    __shared__ char smem[32768];   // [trel 0..7][ks-4 0..3][lane] * 16 B

    const int tid  = threadIdx.x;
    const int wave = tid >> 6;
    const int lane = tid & 63;
    const int lo   = lane & 15;
    const int quad = lane >> 4;
    const int rb    = blockIdx.x >> 4;     // 64 row-blocks
    const int split = blockIdx.x & 15;     // consecutive blocks -> different XCDs
    const int row0 = rb * BM;
    const int C0   = split * (N2 / NSPLIT);
    const int wr = (wave >> 1) * 64;       // wave row-half
    const int wc = (wave & 1) * 64;        // wave col-half
    const int wt = wr >> 4;                // wave row-tile base (0 or 4)

    // --- one-time A staging ---
    const char* Ablk = Af + (size_t)(row0 >> 4) * 8192;   // 8 tiles x 8 KB
    #pragma unroll
    for (int j = 0; j < 8; j++)            // tile j, ks 4..7 -> LDS (4 KB each)
        GLD16(Ablk + (size_t)j * 8192 + 4096 + tid * 16, smem + j * 4096 + tid * 16);
    v8s areg[4][4];                         // tile wt+rt, ks 0..3 -> registers
    #pragma unroll
    for (int rt = 0; rt < 4; rt++)
        #pragma unroll
        for (int ks = 0; ks < 4; ks++)
            areg[rt][ks] = *(const v8s*)(Ablk + (size_t)((wt + rt) * 8 + ks) * 1024 + lane * 16);
    __syncthreads();   // drains the global_load_lds (vmcnt 0) once

    float t0[16], t1[16], t2[16];
    #pragma unroll
    for (int i = 0; i < 16; i++) { t0[i] = -1e30f; t1[i] = -1e30f; t2[i] = -1e30f; }

    for (int nt = 0; nt < NT_PER_SPLIT; ++nt) {
        const char* Bb = Bf + ((size_t)((C0 >> 4) + nt * 8 + (wc >> 4))) * 8192 + lane * 16;
        f32x4 acc[4][4];
        #pragma unroll
        for (int ks = 0; ks < 8; ks++) {
            v8s af[4];
            #pragma unroll
            for (int rt = 0; rt < 4; rt++)
                af[rt] = (ks < 4)
                    ? areg[rt][ks]
                    : *(const v8s*)(smem + (size_t)((wt + rt) * 4 + (ks - 4)) * 1024 + lane * 16);
            #pragma unroll
            for (int ct = 0; ct < 4; ct++) {
                v8s bf = *(const v8s*)(Bb + (size_t)ct * 8192 + ks * 1024);
                #pragma unroll
                for (int rt = 0; rt < 4; rt++) {
                    if (ks == 0)
                        acc[rt][ct] = __builtin_amdgcn_mfma_f32_16x16x32_bf16(
                            af[rt], bf, (f32x4){0.f, 0.f, 0.f, 0.f}, 0, 0, 0);
                    else
                        acc[rt][ct] = __builtin_amdgcn_mfma_f32_16x16x32_bf16(
                            af[rt], bf, acc[rt][ct], 0, 0, 0);
                }
            }
        }
        // fold this N-tile's 64 C-values/lane into the running top3
        #pragma unroll
        for (int rt = 0; rt < 4; rt++)
            #pragma unroll
            for (int r = 0; r < 4; r++) {
                const int i = rt * 4 + r;
                #pragma unroll
                for (int ct = 0; ct < 4; ct++)
                    top3_insert(acc[rt][ct][r], t0[i], t1[i], t2[i]);
            }
    }

    // merge across the 16 lanes sharing rows (different col residues)
    #pragma unroll
    for (int step = 1; step < 16; step <<= 1) {
        #pragma unroll
        for (int i = 0; i < 16; i++) {
            float b0 = __shfl_xor(t0[i], step, 64);
            float b1 = __shfl_xor(t1[i], step, 64);
            float b2 = __shfl_xor(t2[i], step, 64);
            top3_insert(b0, t0[i], t1[i], t2[i]);
            top3_insert(b1, t0[i], t1[i], t2[i]);
            top3_insert(b2, t0[i], t1[i], t2[i]);
        }
    }

    if (lo == 0) {
        #pragma unroll
        for (int rt = 0; rt < 4; rt++)
            #pragma unroll
            for (int r = 0; r < 4; r++) {
                const int i = rt * 4 + r;
                const int row = row0 + wr + rt * 16 + quad * 4 + r;
                float* p = partial + ((size_t)row * NPART + (split * 2 + (wave & 1))) * 3;
                p[0] = t0[i]; p[1] = t1[i]; p[2] = t2[i];
            }
    }
}

__global__ __launch_bounds__(256) void merge_kernel(
        const float* __restrict__ partial, float* __restrict__ out) {
    const int row = blockIdx.x * 256 + threadIdx.x;
    if (row >= N1) return;
    const float* p = partial + (size_t)row * NPART * 3;
    float t0 = -1e30f, t1 = -1e30f, t2 = -1e30f;
    #pragma unroll
    for (int i = 0; i < NPART * 3; i++) top3_insert(p[i], t0, t1, t2);
    out[row] = (t0 + t1 + t2) * (1.0f / 3.0f);
}

extern "C" void kernel_launch(void* const* d_in, const int* in_sizes, int n_in,
                              void* d_out, int out_size, void* d_ws, size_t ws_size,
                              hipStream_t stream) {
    const float* tA = (const float*)d_in[0];
    const float* tB = (const float*)d_in[1];
    float* out = (float*)d_out;

    char* Af = (char*)d_ws;                             // 4 MB frag-packed A
    char* Bf = Af + (size_t)N1 * DIM * 2;               // 8 MB frag-packed B
    float* partial = (float*)(Bf + (size_t)N2 * DIM * 2);

    normalize_repack_kernel<<<(N1 + N2) / 4, 256, 0, stream>>>(tA, tB, Af, Bf);
    gemm_top3_kernel<<<(N1 / BM) * NSPLIT, 256, 0, stream>>>(Af, Bf, partial);
    merge_kernel<<<N1 / 256, 256, 0, stream>>>(partial, out);
}

// Round 12
// 209.204 us; speedup vs baseline: 1.4075x; 1.1584x over previous
//
#include <hip/hip_runtime.h>
#include <hip/hip_bf16.h>
#include <stdint.h>

#define N1 8192
#define N2 16384
#define DIM 256
#define NSPLIT 16
#define BM 128
#define BN 128
#define BK 64
#define COLS_PER_SPLIT (N2 / NSPLIT)        // 1024
#define NT_PER_SPLIT (COLS_PER_SPLIT / BN)  // 8
#define NPART (NSPLIT * 2)                  // 32 partial top3 sets per row

typedef short v8s  __attribute__((ext_vector_type(8)));   // 8 x bf16 bits
typedef float f32x4 __attribute__((ext_vector_type(4)));

#define GLD16(g, l)                                                                         \
  __builtin_amdgcn_global_load_lds((const __attribute__((address_space(1))) uint32_t*)(g),  \
                                   (__attribute__((address_space(3))) uint32_t*)(l), 16, 0, 0)

__device__ __forceinline__ void top3_insert(float v, float& t0, float& t1, float& t2) {
    // invariant t0 >= t1 >= t2; 3 VALU ops
    float nt1 = __builtin_amdgcn_fmed3f(v, t0, t1);
    float nt2 = __builtin_amdgcn_fmed3f(v, t1, t2);
    t0 = fmaxf(t0, v);
    t1 = nt1;
    t2 = nt2;
}

// One wave per row over A then B: fp32 sumsq, rsqrt, emit bf16 normalized row.
__global__ __launch_bounds__(256) void normalize_kernel(
        const float* __restrict__ inA, const float* __restrict__ inB,
        __hip_bfloat16* __restrict__ outA, __hip_bfloat16* __restrict__ outB) {
    const int gw   = blockIdx.x * 4 + (threadIdx.x >> 6);
    const int lane = threadIdx.x & 63;
    const float* in;
    __hip_bfloat16* out;
    int row;
    if (gw < N1) { in = inA; out = outA; row = gw; }
    else         { in = inB; out = outB; row = gw - N1; }
    const float4 v = *(const float4*)(in + (size_t)row * DIM + lane * 4);
    float s = v.x * v.x + v.y * v.y + v.z * v.z + v.w * v.w;
    #pragma unroll
    for (int off = 32; off; off >>= 1) s += __shfl_xor(s, off, 64);
    const float inv = 1.0f / sqrtf(s);
    __hip_bfloat16 o[4];
    o[0] = __float2bfloat16(v.x * inv);
    o[1] = __float2bfloat16(v.y * inv);
    o[2] = __float2bfloat16(v.z * inv);
    o[3] = __float2bfloat16(v.w * inv);
    *(uint2*)(out + (size_t)row * DIM + lane * 4) = *(uint2*)o;
}

// Block: 4 waves over a 128x128 C-tile; wave = 64x64 (4rt x 4ct of 16x16).
// Per K-chunk (BK=64): A 128x64 (16 KB) + B 128x64 (16 KB) staged via
// global_load_lds width=16; XOR swizzle (slot = chunk ^ (row&7)) folded into
// the global-side lane permutation -> conflict-free ds_read_b128.
// __launch_bounds__(256,3): R7's profile showed no pipe saturated (LDS 47%,
// MFMA 33%, VALU 37%) -> latency-bound at 2 waves/SIMD. Budget 170 regs/wave
// (106 arch + 64 AGPR acc) admits 3 blocks/CU; 32 KB LDS keeps the LDS cap
// at 5. (256,4) was a catastrophic squeeze (R5); 3 is the gentle point.
__global__ __launch_bounds__(256, 3) void gemm_top3_kernel(
        const __hip_bfloat16* __restrict__ A, const __hip_bfloat16* __restrict__ B,
        float* __restrict__ partial) {
    __shared__ char smem[16384 + 16384];
    char* tileA = smem;             // [128 rows][8 slots of 16B]
    char* tileB = smem + 16384;     // [128 cols][8 slots of 16B]

    const int tid  = threadIdx.x;
    const int wave = tid >> 6;
    const int lane = tid & 63;
    const int lo   = lane & 15;
    const int quad = lane >> 4;
    const int rb    = blockIdx.x >> 4;     // 64 row-blocks
    const int split = blockIdx.x & 15;     // consecutive blocks -> different XCDs
    const int row0 = rb * BM;
    const int C0   = split * COLS_PER_SPLIT;
    const int wr = (wave >> 1) * 64;       // wave row-half
    const int wc = (wave & 1) * 64;        // wave col-half

    // --- staging lane constants (8 lanes span one row's 8 slots of 16B) ---
    const int lr = lane >> 3;              // 0..7 : row-within-round
    const int s8 = lane & 7;               // 0..7 : physical LDS slot
    const int sx = s8 ^ lr;                // global 16B chunk this lane fetches

    const char* Agbase = (const char*)A + ((size_t)(row0 + wave * 32 + lr)) * 512 + sx * 16;
    const char* Bgbase = (const char*)B + ((size_t)(C0   + wave * 32 + lr)) * 512 + sx * 16;
    char* AldsBase = tileA + wave * 32 * 128;   // + j*1024 per 8-row round
    char* BldsBase = tileB + wave * 32 * 128;

    // --- ds_read offsets (swizzle: slot = (ks*4+quad) ^ (row&7)) ---
    int aoff[2], boff[2];
    #pragma unroll
    for (int ks = 0; ks < 2; ks++) {
        const int swz = ((ks * 4 + quad) ^ (lo & 7)) * 16;
        aoff[ks] = (wr + lo) * 128 + swz;
        boff[ks] = (wc + lo) * 128 + swz;
    }

    float t0[16], t1[16], t2[16];
    #pragma unroll
    for (int i = 0; i < 16; i++) { t0[i] = -1e30f; t1[i] = -1e30f; t2[i] = -1e30f; }

    for (int nt = 0; nt < NT_PER_SPLIT; ++nt) {
        f32x4 acc[4][4];
        #pragma unroll
        for (int kk = 0; kk < 4; kk++) {
            __syncthreads();   // previous chunk's ds_reads done; buffers free
            #pragma unroll
            for (int j = 0; j < 4; j++)
                GLD16(Agbase + (size_t)j * 4096 + kk * 128, AldsBase + j * 1024);
            #pragma unroll
            for (int j = 0; j < 4; j++)
                GLD16(Bgbase + (size_t)nt * 65536 + (size_t)j * 4096 + kk * 128,
                      BldsBase + j * 1024);
            __syncthreads();   // staging drained (vmcnt(0) before barrier)
            #pragma unroll
            for (int ks = 0; ks < 2; ks++) {
                v8s af[4];
                #pragma unroll
                for (int rt = 0; rt < 4; rt++)
                    af[rt] = *(const v8s*)(tileA + aoff[ks] + rt * 2048);
                #pragma unroll
                for (int ct = 0; ct < 4; ct++) {
                    v8s bf = *(const v8s*)(tileB + boff[ks] + ct * 2048);
                    #pragma unroll
                    for (int rt = 0; rt < 4; rt++) {
                        if (kk == 0 && ks == 0)
                            acc[rt][ct] = __builtin_amdgcn_mfma_f32_16x16x32_bf16(
                                af[rt], bf, (f32x4){0.f, 0.f, 0.f, 0.f}, 0, 0, 0);
                        else
                            acc[rt][ct] = __builtin_amdgcn_mfma_f32_16x16x32_bf16(
                                af[rt], bf, acc[rt][ct], 0, 0, 0);
                    }
                }
            }
        }
        // fold this N-tile's 64 C-values/lane into the running top3
        #pragma unroll
        for (int rt = 0; rt < 4; rt++)
            #pragma unroll
            for (int r = 0; r < 4; r++) {
                const int i = rt * 4 + r;
                #pragma unroll
                for (int ct = 0; ct < 4; ct++)
                    top3_insert(acc[rt][ct][r], t0[i], t1[i], t2[i]);
            }
    }

    // merge across the 16 lanes sharing rows (different col residues)
    #pragma unroll
    for (int step = 1; step < 16; step <<= 1) {
        #pragma unroll
        for (int i = 0; i < 16; i++) {
            float b0 = __shfl_xor(t0[i], step, 64);
            float b1 = __shfl_xor(t1[i], step, 64);
            float b2 = __shfl_xor(t2[i], step, 64);
            top3_insert(b0, t0[i], t1[i], t2[i]);
            top3_insert(b1, t0[i], t1[i], t2[i]);
            top3_insert(b2, t0[i], t1[i], t2[i]);
        }
    }

    if (lo == 0) {
        #pragma unroll
        for (int rt = 0; rt < 4; rt++)
            #pragma unroll
            for (int r = 0; r < 4; r++) {
                const int i = rt * 4 + r;
                const int row = row0 + wr + rt * 16 + quad * 4 + r;
                float* p = partial + ((size_t)row * NPART + (split * 2 + (wave & 1))) * 3;
                p[0] = t0[i]; p[1] = t1[i]; p[2] = t2[i];
            }
    }
}

__global__ __launch_bounds__(256) void merge_kernel(
        const float* __restrict__ partial, float* __restrict__ out) {
    const int row = blockIdx.x * 256 + threadIdx.x;
    if (row >= N1) return;
    const float* p = partial + (size_t)row * NPART * 3;
    float t0 = -1e30f, t1 = -1e30f, t2 = -1e30f;
    #pragma unroll
    for (int i = 0; i < NPART * 3; i++) top3_insert(p[i], t0, t1, t2);
    out[row] = (t0 + t1 + t2) * (1.0f / 3.0f);
}

extern "C" void kernel_launch(void* const* d_in, const int* in_sizes, int n_in,
                              void* d_out, int out_size, void* d_ws, size_t ws_size,
                              hipStream_t stream) {
    const float* tA = (const float*)d_in[0];
    const float* tB = (const float*)d_in[1];
    float* out = (float*)d_out;

    __hip_bfloat16* An = (__hip_bfloat16*)d_ws;
    __hip_bfloat16* Bn = An + (size_t)N1 * DIM;
    float* partial = (float*)(Bn + (size_t)N2 * DIM);

    normalize_kernel<<<(N1 + N2) / 4, 256, 0, stream>>>(tA, tB, An, Bn);
    gemm_top3_kernel<<<(N1 / BM) * NSPLIT, 256, 0, stream>>>(An, Bn, partial);
    merge_kernel<<<N1 / 256, 256, 0, stream>>>(partial, out);
}

// Round 13
// 155.561 us; speedup vs baseline: 1.8928x; 1.3448x over previous
//
#include <hip/hip_runtime.h>
#include <hip/hip_bf16.h>
#include <stdint.h>

#define N1 8192
#define N2 16384
#define DIM 256
#define NSPLIT 16
#define BM 128
#define BN 128
#define BK 64
#define COLS_PER_SPLIT (N2 / NSPLIT)        // 1024
#define NT_PER_SPLIT (COLS_PER_SPLIT / BN)  // 8
#define NPART (NSPLIT * 2)                  // 32 partial top3 sets per row

typedef short v8s  __attribute__((ext_vector_type(8)));   // 8 x bf16 bits
typedef float f32x4 __attribute__((ext_vector_type(4)));

#define GLD16(g, l)                                                                         \
  __builtin_amdgcn_global_load_lds((const __attribute__((address_space(1))) uint32_t*)(g),  \
                                   (__attribute__((address_space(3))) uint32_t*)(l), 16, 0, 0)

__device__ __forceinline__ void top3_insert(float v, float& t0, float& t1, float& t2) {
    // invariant t0 >= t1 >= t2; 3 VALU ops
    float nt1 = __builtin_amdgcn_fmed3f(v, t0, t1);
    float nt2 = __builtin_amdgcn_fmed3f(v, t1, t2);
    t0 = fmaxf(t0, v);
    t1 = nt1;
    t2 = nt2;
}

// One wave per row over A then B: fp32 sumsq, rsqrt, emit bf16 normalized row.
__global__ __launch_bounds__(256) void normalize_kernel(
        const float* __restrict__ inA, const float* __restrict__ inB,
        __hip_bfloat16* __restrict__ outA, __hip_bfloat16* __restrict__ outB) {
    const int gw   = blockIdx.x * 4 + (threadIdx.x >> 6);
    const int lane = threadIdx.x & 63;
    const float* in;
    __hip_bfloat16* out;
    int row;
    if (gw < N1) { in = inA; out = outA; row = gw; }
    else         { in = inB; out = outB; row = gw - N1; }
    const float4 v = *(const float4*)(in + (size_t)row * DIM + lane * 4);
    float s = v.x * v.x + v.y * v.y + v.z * v.z + v.w * v.w;
    #pragma unroll
    for (int off = 32; off; off >>= 1) s += __shfl_xor(s, off, 64);
    const float inv = 1.0f / sqrtf(s);
    __hip_bfloat16 o[4];
    o[0] = __float2bfloat16(v.x * inv);
    o[1] = __float2bfloat16(v.y * inv);
    o[2] = __float2bfloat16(v.z * inv);
    o[3] = __float2bfloat16(v.w * inv);
    *(uint2*)(out + (size_t)row * DIM + lane * 4) = *(uint2*)o;
}

// Block: 4 waves over a 128x128 C-tile; wave = 64x64 (4rt x 4ct of 16x16).
// PIPELINED K-loop (AITER-style): double-buffered 32 KB chunk buffers, ONE
// barrier per BK=64 chunk. After the barrier, the next chunk's
// global_load_lds is issued into the idle buffer, then compute reads the
// current buffer. The compiler's mandatory vmcnt(0)-before-barrier then
// drains a prefetch that has had a full compute phase (~1000 cyc) to land,
// so staging (~31 us of L2->LDS DMA) overlaps MFMA (~33 us) instead of
// serializing with it (R7's 2-barrier loop: 86 us).
// Registers: ~124 arch + 64 AGPR -> hard 2 blocks/CU ((256,3)/(256,4)
// spill, R11/R5); 64 KB LDS keeps 2 blocks/CU.
// XOR swizzle (slot = chunk ^ (row&7)) folded into the global-side lane
// permutation -> conflict-free ds_read_b128, zero ds_writes.
__global__ __launch_bounds__(256, 2) void gemm_top3_kernel(
        const __hip_bfloat16* __restrict__ A, const __hip_bfloat16* __restrict__ B,
        float* __restrict__ partial) {
    __shared__ char smem[2 * 32768];       // [buf][A 16K | B 16K]

    const int tid  = threadIdx.x;
    const int wave = tid >> 6;
    const int lane = tid & 63;
    const int lo   = lane & 15;
    const int quad = lane >> 4;
    const int rb    = blockIdx.x >> 4;     // 64 row-blocks
    const int split = blockIdx.x & 15;     // consecutive blocks -> different XCDs
    const int row0 = rb * BM;
    const int C0   = split * COLS_PER_SPLIT;
    const int wr = (wave >> 1) * 64;       // wave row-half
    const int wc = (wave & 1) * 64;        // wave col-half

    // --- staging lane constants (8 lanes span one row's 8 slots of 16B) ---
    const int lr = lane >> 3;              // 0..7 : row-within-round
    const int s8 = lane & 7;               // 0..7 : physical LDS slot
    const int sx = s8 ^ lr;                // global 16B chunk this lane fetches

    const char* Agbase = (const char*)A + ((size_t)(row0 + wave * 32 + lr)) * 512 + sx * 16;
    const char* Bgbase = (const char*)B + ((size_t)(C0   + wave * 32 + lr)) * 512 + sx * 16;
    const int ldsWaveOff = wave * 32 * 128;   // within a 16 KB tile

    // --- ds_read offsets (swizzle: slot = (ks*4+quad) ^ (row&7)) ---
    int aoff[2], boff[2];
    #pragma unroll
    for (int ks = 0; ks < 2; ks++) {
        const int swz = ((ks * 4 + quad) ^ (lo & 7)) * 16;
        aoff[ks] = (wr + lo) * 128 + swz;
        boff[ks] = (wc + lo) * 128 + swz;
    }

    float t0[16], t1[16], t2[16];
    #pragma unroll
    for (int i = 0; i < 16; i++) { t0[i] = -1e30f; t1[i] = -1e30f; t2[i] = -1e30f; }

    // stage(nt, kk) into buffer buf
    #define STAGE(nt_, kk_, buf_)                                                     \
        do {                                                                          \
            char* Al = smem + (buf_) * 32768 + ldsWaveOff;                            \
            char* Bl = smem + (buf_) * 32768 + 16384 + ldsWaveOff;                    \
            _Pragma("unroll")                                                         \
            for (int j = 0; j < 4; j++)                                               \
                GLD16(Agbase + (size_t)j * 4096 + (kk_) * 128, Al + j * 1024);        \
            _Pragma("unroll")                                                         \
            for (int j = 0; j < 4; j++)                                               \
                GLD16(Bgbase + (size_t)(nt_) * 65536 + (size_t)j * 4096 + (kk_) * 128,\
                      Bl + j * 1024);                                                 \
        } while (0)

    STAGE(0, 0, 0);   // prologue; drained by the first barrier

    for (int nt = 0; nt < NT_PER_SPLIT; ++nt) {
        f32x4 acc[4][4];
        #pragma unroll
        for (int kk = 0; kk < 4; kk++) {
            const int buf = kk & 1;        // 4 flips/nt -> invariant across nt
            __syncthreads();               // drains prefetch (vmcnt 0) + frees buf^1
            // prefetch next chunk into the other buffer (none after the last)
            if (kk < 3) {
                STAGE(nt, kk + 1, buf ^ 1);
            } else if (nt < NT_PER_SPLIT - 1) {
                STAGE(nt + 1, 0, buf ^ 1);
            }
            // compute chunk (nt,kk) from buf
            const char* tA = smem + buf * 32768;
            const char* tB = smem + buf * 32768 + 16384;
            #pragma unroll
            for (int ks = 0; ks < 2; ks++) {
                v8s af[4];
                #pragma unroll
                for (int rt = 0; rt < 4; rt++)
                    af[rt] = *(const v8s*)(tA + aoff[ks] + rt * 2048);
                #pragma unroll
                for (int ct = 0; ct < 4; ct++) {
                    v8s bf = *(const v8s*)(tB + boff[ks] + ct * 2048);
                    #pragma unroll
                    for (int rt = 0; rt < 4; rt++) {
                        if (kk == 0 && ks == 0)
                            acc[rt][ct] = __builtin_amdgcn_mfma_f32_16x16x32_bf16(
                                af[rt], bf, (f32x4){0.f, 0.f, 0.f, 0.f}, 0, 0, 0);
                        else
                            acc[rt][ct] = __builtin_amdgcn_mfma_f32_16x16x32_bf16(
                                af[rt], bf, acc[rt][ct], 0, 0, 0);
                    }
                }
            }
        }
        // fold this N-tile's 64 C-values/lane into the running top3
        #pragma unroll
        for (int rt = 0; rt < 4; rt++)
            #pragma unroll
            for (int r = 0; r < 4; r++) {
                const int i = rt * 4 + r;
                #pragma unroll
                for (int ct = 0; ct < 4; ct++)
                    top3_insert(acc[rt][ct][r], t0[i], t1[i], t2[i]);
            }
    }

    // merge across the 16 lanes sharing rows (different col residues)
    #pragma unroll
    for (int step = 1; step < 16; step <<= 1) {
        #pragma unroll
        for (int i = 0; i < 16; i++) {
            float b0 = __shfl_xor(t0[i], step, 64);
            float b1 = __shfl_xor(t1[i], step, 64);
            float b2 = __shfl_xor(t2[i], step, 64);
            top3_insert(b0, t0[i], t1[i], t2[i]);
            top3_insert(b1, t0[i], t1[i], t2[i]);
            top3_insert(b2, t0[i], t1[i], t2[i]);
        }
    }

    if (lo == 0) {
        #pragma unroll
        for (int rt = 0; rt < 4; rt++)
            #pragma unroll
            for (int r = 0; r < 4; r++) {
                const int i = rt * 4 + r;
                const int row = row0 + wr + rt * 16 + quad * 4 + r;
                float* p = partial + ((size_t)row * NPART + (split * 2 + (wave & 1))) * 3;
                p[0] = t0[i]; p[1] = t1[i]; p[2] = t2[i];
            }
    }
}

__global__ __launch_bounds__(256) void merge_kernel(
        const float* __restrict__ partial, float* __restrict__ out) {
    const int row = blockIdx.x * 256 + threadIdx.x;
    if (row >= N1) return;
    const float* p = partial + (size_t)row * NPART * 3;
    float t0 = -1e30f, t1 = -1e30f, t2 = -1e30f;
    #pragma unroll
    for (int i = 0; i < NPART * 3; i++) top3_insert(p[i], t0, t1, t2);
    out[row] = (t0 + t1 + t2) * (1.0f / 3.0f);
}

extern "C" void kernel_launch(void* const* d_in, const int* in_sizes, int n_in,
                              void* d_out, int out_size, void* d_ws, size_t ws_size,
                              hipStream_t stream) {
    const float* tA = (const float*)d_in[0];
    const float* tB = (const float*)d_in[1];
    float* out = (float*)d_out;

    __hip_bfloat16* An = (__hip_bfloat16*)d_ws;
    __hip_bfloat16* Bn = An + (size_t)N1 * DIM;
    float* partial = (float*)(Bn + (size_t)N2 * DIM);

    normalize_kernel<<<(N1 + N2) / 4, 256, 0, stream>>>(tA, tB, An, Bn);
    gemm_top3_kernel<<<(N1 / BM) * NSPLIT, 256, 0, stream>>>(An, Bn, partial);
    merge_kernel<<<N1 / 256, 256, 0, stream>>>(partial, out);
}